// Round 6
// baseline (259.773 us; speedup 1.0000x reference)
//
#include <hip/hip_runtime.h>

// VolumeRenderer: N=65536 rays, L=192 samples.
//   delta[l] = depth[l+1]-depth[l] (last = 1e10)
//   alpha = 1 - exp(-relu(sigma)*delta)
//   w     = alpha * (1 - alpha + 1e-10)     (cumprod over size-1 axis = identity)
//   color = sum_l sigmoid(rgb[l]) * w[l]     -> (N,3)
//   depth_out = sum_l w[l]*depth[l]          -> (N,1)
//
// v6: supply-side read-locality attack. Evidence: harness fills hit 6.85 TB/s
// write @9.4% occupancy (memory healthy); our reads pinned at 2.6-3.0 TB/s
// across 4 structures with >=20KB/CU outstanding (Little's law: demand >>
// supply) => supply-side cap for our pattern. v5b (nt loads) = first real win
// (97 -> ~83 us kernel). Remaining suspects: 49K short-run stream heads
// scattered over 252 MB (HBM row / MALL-bank thrash) + 25% duplicate lanes.
// Changes (one theory): dense dwordx3 lane map (64/64 lanes useful), RPW=16
// (12-36 KB sequential run per stream head, 12K heads), bijective XCD swizzle
// (each XCD reads one contiguous 31.5 MB slice), keep nt + depth-2 pipeline.
//
// Layout: wave = ray; lane l owns samples 3l..3l+2.
//   depth/sigma: dwordx3 @ float 3l (64x12B = 768B dense)
//   rgb:        3x dwordx3 @ float 9l,9l+3,9l+6 (64x36B = 2304B dense)

constexpr int L = 192;
constexpr int RPW = 16;          // rays per wave, sequential (long stream runs)
constexpr int NXCD = 8;

typedef float vf3 __attribute__((ext_vector_type(3)));

__device__ __forceinline__ float fast_sigmoid(float x) {
    return __builtin_amdgcn_rcpf(1.0f + __expf(-x));
}

__device__ __forceinline__ vf3 ldnt3(const float* p) {
    return __builtin_nontemporal_load((const vf3*)p);
}

__global__ __launch_bounds__(256) void volrender_kernel(
    const float* __restrict__ depth, const float* __restrict__ rgb,
    const float* __restrict__ sigma, float* __restrict__ out, int n_rays)
{
    const int lane = threadIdx.x & 63;

    // bijective XCD swizzle: grid=1024, XCD x owns logical blocks [128x,128x+128)
    // -> each XCD's CUs march one contiguous 1/8 address slice.
    const int nb  = gridDim.x;                  // 1024 (divisible by 8)
    const int cpx = nb / NXCD;                  // 128
    const int bid = (blockIdx.x % NXCD) * cpx + blockIdx.x / NXCD;

    const int wid  = (bid << 2) + (threadIdx.x >> 6);
    const int ray0 = wid * RPW;

    // per-ray payload: depth vf3 + sigma vf3 + 3x rgb vf3 = 15 VGPRs; x2 buffers
    vf3 d_a, s_a, c0_a, c1_a, c2_a;
    vf3 d_b, s_b, c0_b, c1_b, c2_b;

    {   // prologue: ray0 loads (independent, issued together)
        const long long db = (long long)ray0 * L + 3 * lane;
        const long long cb = (long long)ray0 * (3 * L) + 9 * lane;
        d_a  = ldnt3(depth + db);
        s_a  = ldnt3(sigma + db);
        c0_a = ldnt3(rgb + cb);
        c1_a = ldnt3(rgb + cb + 3);
        c2_a = ldnt3(rgb + cb + 6);
    }

    #pragma unroll
    for (int i = 0; i < RPW; ++i) {
        // ---- prefetch next ray before consuming current ----
        if (i + 1 < RPW) {
            const int rn = ray0 + i + 1;
            const long long db = (long long)rn * L + 3 * lane;
            const long long cb = (long long)rn * (3 * L) + 9 * lane;
            d_b  = ldnt3(depth + db);
            s_b  = ldnt3(sigma + db);
            c0_b = ldnt3(rgb + cb);
            c1_b = ldnt3(rgb + cb + 3);
            c2_b = ldnt3(rgb + cb + 6);
        }

        // ---- compute current ray ----
        // neighbor's first depth sample = depth[3(l+1)]; lane 63 guard -> 1e10
        const float dn  = __shfl(d_a.x, lane + 1);
        const float dl0 = d_a.y - d_a.x;
        const float dl1 = d_a.z - d_a.y;
        const float dl2 = (lane == 63) ? 1e10f : (dn - d_a.z);

        const float a0 = 1.0f - __expf(-fmaxf(s_a.x, 0.0f) * dl0);
        const float a1 = 1.0f - __expf(-fmaxf(s_a.y, 0.0f) * dl1);
        const float a2 = 1.0f - __expf(-fmaxf(s_a.z, 0.0f) * dl2);
        const float w0 = a0 * (1.0f - a0 + 1e-10f);
        const float w1 = a1 * (1.0f - a1 + 1e-10f);
        const float w2 = a2 * (1.0f - a2 + 1e-10f);

        // rgb vf3s of lane l: c0=(r0,g0,b0) c1=(r1,g1,b1) c2=(r2,g2,b2)
        float cr = fast_sigmoid(c0_a.x) * w0 + fast_sigmoid(c1_a.x) * w1
                 + fast_sigmoid(c2_a.x) * w2;
        float cg = fast_sigmoid(c0_a.y) * w0 + fast_sigmoid(c1_a.y) * w1
                 + fast_sigmoid(c2_a.y) * w2;
        float cbl= fast_sigmoid(c0_a.z) * w0 + fast_sigmoid(c1_a.z) * w1
                 + fast_sigmoid(c2_a.z) * w2;
        float dd = d_a.x * w0 + d_a.y * w1 + d_a.z * w2;

        // ---- wave butterfly reduction (all 64 lanes carry real data) ----
        #pragma unroll
        for (int off = 32; off > 0; off >>= 1) {
            cr  += __shfl_xor(cr, off);
            cg  += __shfl_xor(cg, off);
            cbl += __shfl_xor(cbl, off);
            dd  += __shfl_xor(dd, off);
        }

        if (lane == 0) {
            const int ray = ray0 + i;
            out[ray * 3 + 0] = cr;
            out[ray * 3 + 1] = cg;
            out[ray * 3 + 2] = cbl;
            out[(long long)n_rays * 3 + ray] = dd;   // depth block after color
        }

        // rotate pipeline buffers (register renaming under full unroll)
        d_a = d_b; s_a = s_b; c0_a = c0_b; c1_a = c1_b; c2_a = c2_b;
    }
}

extern "C" void kernel_launch(void* const* d_in, const int* in_sizes, int n_in,
                              void* d_out, int out_size, void* d_ws, size_t ws_size,
                              hipStream_t stream) {
    const float* depth = (const float*)d_in[0];
    const float* rgb   = (const float*)d_in[1];
    const float* sigma = (const float*)d_in[2];
    float* out = (float*)d_out;
    const int n_rays = in_sizes[0] / L;          // 65536
    const int waves  = n_rays / RPW;             // 4096 waves
    const int blocks = waves / 4;                // 1024 blocks x 256 threads
    volrender_kernel<<<blocks, 256, 0, stream>>>(depth, rgb, sigma, out, n_rays);
}